// Round 9
// baseline (581.276 us; speedup 1.0000x reference)
//
#include <hip/hip_runtime.h>

typedef unsigned short u16;
typedef unsigned int u32;
typedef __attribute__((ext_vector_type(8))) _Float16 half8;
typedef __attribute__((ext_vector_type(2))) __fp16 fp16x2;
typedef __attribute__((ext_vector_type(16))) float f32x16;

#define MFMA32(A, B, C) __builtin_amdgcn_mfma_f32_32x32x16_f16(A, B, C, 0, 0, 0)

constexpr int BN = 8;     // batches
constexpr int S = 4096;   // seq len
constexpr int D = 256;    // feature dim
constexpr int KB = 32;    // K/V tile rows
constexpr int NT = S / KB;            // 128 tiles
constexpr int TILE_U16 = KB * D;      // 8192 u16 = 16 KiB per image
constexpr int TP_U16 = 2 * TILE_U16;  // 32 KiB tile pack (enc|encT)

__device__ __forceinline__ u32 pk2h(float a, float b) {  // RNE (conversion path)
  union { _Float16 h[2]; u32 u; } x;
  x.h[0] = (_Float16)a; x.h[1] = (_Float16)b;
  return x.u;
}

__device__ __forceinline__ u32 pkrtz(float a, float b) {  // 1-inst pack (hot loop)
  union { fp16x2 h; u32 u; } x;
  x.h = __builtin_amdgcn_cvt_pkrtz(a, b);
  return x.u;
}

// ---------------------------------------------------------------------------
// Convert enc (f32) into MFMA-fragment-ordered f16 tile packs (validated):
// pack(b,t) = [ enc_img | encT_img ], 32 KiB contiguous. Fragment order means
// a wave's A-operand for one MFMA is a contiguous lane-linear 1 KiB block --
// readable directly with one global_load_dwordx4 per lane, fully coalesced.
// ---------------------------------------------------------------------------
__global__ __launch_bounds__(256) void convert_enc(const float* __restrict__ enc,
                                                   u16* __restrict__ ws) {
  const int blk = blockIdx.x;
  const int b = blk & 7;
  const int tp = blk >> 3;  // tile pair 0..63
  const int tid = threadIdx.x;

  const float* encb = enc + (size_t)b * S * D;

  // ---- phase A: enc images, 2 tiles x 1024 groups ----
#pragma unroll
  for (int it = 0; it < 8; ++it) {
    int gg = it * 256 + tid;        // 0..2047
    int t = tp * 2 + (gg >> 10);
    int g = gg & 1023;              // (c*2+h)*32 + i
    int i = g & 31;
    int ch = g >> 5;
    int d0 = ch * 8;
    const float* src = encb + (size_t)(t * 32 + i) * D + d0;
    float4 x = *(const float4*)src;
    float4 y = *(const float4*)(src + 4);
    uint4 o;
    o.x = pk2h(x.x, x.y); o.y = pk2h(x.z, x.w);
    o.z = pk2h(y.x, y.y); o.w = pk2h(y.z, y.w);
    *(uint4*)(ws + (size_t)(b * NT + t) * TP_U16 + g * 8) = o;
  }

  // ---- phase B: encT images, 2 tiles x 128 blocklets (8i x 8d) ----
  {
    int t = tp * 2 + (tid >> 7);
    int r = tid & 127;
    int o = r >> 5;       // i-oct: ic=o>>1, h=o&1
    int e = r & 31;       // d-oct
    int i0 = o * 8;
    int d0 = e * 8;
    float v[8][8];
#pragma unroll
    for (int rr = 0; rr < 8; ++rr) {
      const float* src = encb + (size_t)(t * 32 + i0 + rr) * D + d0;
      *(float4*)&v[rr][0] = *(const float4*)src;
      *(float4*)&v[rr][4] = *(const float4*)(src + 4);
    }
    int dsub = e >> 2;
    u16* dst = ws + (size_t)(b * NT + t) * TP_U16 + TILE_U16 +
               ((dsub * 4 + o) * 32 + (e & 3) * 8) * 8;
#pragma unroll
    for (int k = 0; k < 8; ++k) {
      uint4 q;
      q.x = pk2h(v[0][k], v[1][k]); q.y = pk2h(v[2][k], v[3][k]);
      q.z = pk2h(v[4][k], v[5][k]); q.w = pk2h(v[6][k], v[7][k]);
      *(uint4*)(dst + k * 8) = q;
    }
  }
}

// ---------------------------------------------------------------------------
// Flash attention, BARRIER-FREE main loop: A-fragments read DIRECTLY from the
// fragment-ordered global images (L1 broadcasts across the 4 waves of a
// stream; no LDS staging, no __syncthreads until the final merge).
// 256 blocks x 512 thr (4 q-waves x 32 q) x 2 K-streams (kh=w>>2), stream kh
// does tiles t=2j+kh. Per pass: QK(t) | PV(t-1) | SM(t) -- waves free-run.
// LDS (70 KiB) used only for the end-of-kernel split-K merge.
// ---------------------------------------------------------------------------
__global__ __launch_bounds__(512, 2) void attn_kernel(const u16* __restrict__ ws_img,
                                                      const float* __restrict__ dec,
                                                      float* __restrict__ out) {
  __shared__ float fb[17680];  // merge scratch: 16*64*17 + pad + 256 ml

  const int tid = threadIdx.x;
  const int w = tid >> 6;
  const int wq = w & 3;
  const int kh = w >> 2;
  const int lane = tid & 63;
  const int h = lane >> 5;
  const int l31 = lane & 31;

  const int blk = blockIdx.x;
  const int b = blk & 7;               // batch -> XCD affinity
  const int q0 = (blk >> 3) << 7;      // QBLK = 128
  const int qw = q0 + wq * 32;

  const char* packs = (const char*)(ws_img + (size_t)b * NT * TP_U16);
  const float* decb = dec + (size_t)b * S * D;

  // ---- Q fragments (B-operand): lane q=l31, k=c*16+h*8+j; pre-scaled log2e ----
  const float LOG2E = 1.4426950408889634f;
  half8 qf[16];
#pragma unroll
  for (int c = 0; c < 16; ++c) {
    const float* p = decb + (size_t)(qw + l31) * D + c * 16 + h * 8;
    float4 x = *(const float4*)p;
    float4 y = *(const float4*)(p + 4);
    union { u32 u[4]; half8 v; } uu;
    uu.u[0] = pk2h(x.x * LOG2E, x.y * LOG2E);
    uu.u[1] = pk2h(x.z * LOG2E, x.w * LOG2E);
    uu.u[2] = pk2h(y.x * LOG2E, y.y * LOG2E);
    uu.u[3] = pk2h(y.z * LOG2E, y.w * LOG2E);
    qf[c] = uu.v;
  }

  f32x16 acc[8] = {};   // O^T: [dsub]; lane: q=l31, d=dsub*32+(r&3)+8*(r>>2)+4h
  float mrun = -1e30f;  // running max (log2 domain)
  float lrun = 0.f;

  const int eoff = h * 512 + l31 * 16;  // lane offset within a fragment group pair

  // QK(t): S^T = enc . Q^T, dual chain, A-frags straight from global
  auto qkf = [&](int t) -> f32x16 {
    const char* eb = packs + (size_t)t * 32768;
    f32x16 s0 = {}, s1 = {};
    __builtin_amdgcn_s_setprio(1);
#pragma unroll
    for (int c = 0; c < 16; c += 2) {
      half8 a0 = *(const half8*)(eb + (c + 0) * 1024 + eoff);
      half8 a1 = *(const half8*)(eb + (c + 1) * 1024 + eoff);
      s0 = MFMA32(a0, qf[c + 0], s0);
      s1 = MFMA32(a1, qf[c + 1], s1);
    }
    __builtin_amdgcn_s_setprio(0);
    return s0 + s1;
  };

  // PV(t): O^T += encT . P^T
  auto pvf = [&](int t, const half8* bfr) {
    const char* tb = packs + (size_t)t * 32768 + 16384;
    __builtin_amdgcn_s_setprio(1);
#pragma unroll
    for (int ic = 0; ic < 2; ++ic) {
#pragma unroll
      for (int ds = 0; ds < 8; ++ds) {
        half8 vf = *(const half8*)(tb + ((ds * 2 + ic) * 2) * 512 + eoff);
        acc[ds] = MFMA32(vf, bfr[ic], acc[ds]);
      }
    }
    __builtin_amdgcn_s_setprio(0);
  };

  // SM(t): online softmax (log2 domain), defer-max, pack -> bfr
  auto smf = [&](f32x16 st, half8* bfr) {
    float x0 = fmaxf(fmaxf(st[0], st[1]), fmaxf(st[2], st[3]));
    float x1 = fmaxf(fmaxf(st[4], st[5]), fmaxf(st[6], st[7]));
    float x2 = fmaxf(fmaxf(st[8], st[9]), fmaxf(st[10], st[11]));
    float x3 = fmaxf(fmaxf(st[12], st[13]), fmaxf(st[14], st[15]));
    float tm = fmaxf(fmaxf(x0, x1), fmaxf(x2, x3));
    tm = fmaxf(tm, __shfl_xor(tm, 32));
    if (__any(tm > mrun + 11.5f)) {
      float mnew = fmaxf(mrun, tm);
      float alpha = __builtin_amdgcn_exp2f(mrun - mnew);
      mrun = mnew;
      lrun *= alpha;
#pragma unroll
      for (int ds = 0; ds < 8; ++ds)
#pragma unroll
        for (int r = 0; r < 16; ++r) acc[ds][r] *= alpha;
    }
#pragma unroll
    for (int r = 0; r < 16; ++r) st[r] = __builtin_amdgcn_exp2f(st[r] - mrun);
    float y0 = (st[0] + st[1]) + (st[2] + st[3]);
    float y1 = (st[4] + st[5]) + (st[6] + st[7]);
    float y2 = (st[8] + st[9]) + (st[10] + st[11]);
    float y3 = (st[12] + st[13]) + (st[14] + st[15]);
    float rs = (y0 + y1) + (y2 + y3);
    rs += __shfl_xor(rs, 32);
    lrun += rs;

    u32 pkw[8];
#pragma unroll
    for (int rq = 0; rq < 4; ++rq) {
      pkw[rq * 2 + 0] = pkrtz(st[rq * 4 + 0], st[rq * 4 + 1]);
      pkw[rq * 2 + 1] = pkrtz(st[rq * 4 + 2], st[rq * 4 + 3]);
    }
#pragma unroll
    for (int ic = 0; ic < 2; ++ic) {
      u32 own0 = pkw[(2 * ic + h) * 2 + 0];
      u32 own1 = pkw[(2 * ic + h) * 2 + 1];
      u32 send0 = pkw[(2 * ic + 1 - h) * 2 + 0];
      u32 send1 = pkw[(2 * ic + 1 - h) * 2 + 1];
      u32 r0 = (u32)__shfl_xor((int)send0, 32);
      u32 r1 = (u32)__shfl_xor((int)send1, 32);
      union { u32 u[4]; half8 v; } bb;
      bb.u[0] = h ? r0 : own0;
      bb.u[1] = h ? r1 : own1;
      bb.u[2] = h ? own0 : r0;
      bb.u[3] = h ? own1 : r1;
      bfr[ic] = bb.v;
    }
  };

  half8 bfrA[2], bfrB[2];

  // pass j=0 (peeled: no PV yet)
  {
    f32x16 st = qkf(kh);
    smf(st, bfrA);
  }

#pragma unroll 1
  for (int j = 1; j < 64; ++j) {
    const int t = 2 * j + kh;
    f32x16 st = qkf(t);       // QK(t)   [MFMA + vmem]
    pvf(t - 2, bfrA);         // PV(t-1) [MFMA + vmem, independent]
    smf(st, bfrB);            // SM(t)   [VALU] -- other waves' MFMA covers this
    bfrA[0] = bfrB[0]; bfrA[1] = bfrB[1];
  }

  // drain: PV of last tile
  pvf(126 + kh, bfrA);

  // ---- merge the two K-streams through LDS (r4-validated, XS=17) ----
  constexpr int XS = 17;
  float* mlb = fb + 17408;

  __syncthreads();

  if (kh == 1) {
    if (lane < 32) {
      mlb[wq * 64 + lane] = mrun;
      mlb[wq * 64 + 32 + lane] = lrun;
    }
#pragma unroll
    for (int d4 = 0; d4 < 4; ++d4) {
      float* dst = fb + ((wq * 4 + d4) * 64 + lane) * XS;
#pragma unroll
      for (int r4 = 0; r4 < 4; ++r4) {
        float4 v;
        v.x = acc[d4][r4 * 4 + 0]; v.y = acc[d4][r4 * 4 + 1];
        v.z = acc[d4][r4 * 4 + 2]; v.w = acc[d4][r4 * 4 + 3];
        *(float4*)(dst + r4 * 4) = v;
      }
    }
  }
  __syncthreads();

  float a0 = 0.f, a1 = 0.f, inv = 0.f;
  const int q = qw + l31;
  float* orow = out + ((size_t)(b * S + q)) * D;
  if (kh == 0) {
    float m1 = mlb[wq * 64 + l31];
    float l1 = mlb[wq * 64 + 32 + l31];
    float mn = fmaxf(mrun, m1);
    a0 = __builtin_amdgcn_exp2f(mrun - mn);
    a1 = __builtin_amdgcn_exp2f(m1 - mn);
    inv = 1.0f / (a0 * lrun + a1 * l1);
#pragma unroll
    for (int d4 = 0; d4 < 4; ++d4) {
      const float* src = fb + ((wq * 4 + d4) * 64 + lane) * XS;
#pragma unroll
      for (int rq = 0; rq < 4; ++rq) {
        float4 u = *(const float4*)(src + rq * 4);
        int d = d4 * 32 + rq * 8 + h * 4;
        float4 o;
        o.x = (a0 * acc[d4][rq * 4 + 0] + a1 * u.x) * inv;
        o.y = (a0 * acc[d4][rq * 4 + 1] + a1 * u.y) * inv;
        o.z = (a0 * acc[d4][rq * 4 + 2] + a1 * u.z) * inv;
        o.w = (a0 * acc[d4][rq * 4 + 3] + a1 * u.w) * inv;
        *(float4*)(orow + d) = o;
      }
    }
  }
  __syncthreads();

  if (kh == 1) {
#pragma unroll
    for (int d4 = 0; d4 < 4; ++d4) {
      float* dst = fb + ((wq * 4 + d4) * 64 + lane) * XS;
#pragma unroll
      for (int r4 = 0; r4 < 4; ++r4) {
        float4 v;
        v.x = acc[d4 + 4][r4 * 4 + 0]; v.y = acc[d4 + 4][r4 * 4 + 1];
        v.z = acc[d4 + 4][r4 * 4 + 2]; v.w = acc[d4 + 4][r4 * 4 + 3];
        *(float4*)(dst + r4 * 4) = v;
      }
    }
  }
  __syncthreads();

  if (kh == 0) {
#pragma unroll
    for (int d4 = 0; d4 < 4; ++d4) {
      const float* src = fb + ((wq * 4 + d4) * 64 + lane) * XS;
#pragma unroll
      for (int rq = 0; rq < 4; ++rq) {
        float4 u = *(const float4*)(src + rq * 4);
        int d = (d4 + 4) * 32 + rq * 8 + h * 4;
        float4 o;
        o.x = (a0 * acc[d4 + 4][rq * 4 + 0] + a1 * u.x) * inv;
        o.y = (a0 * acc[d4 + 4][rq * 4 + 1] + a1 * u.y) * inv;
        o.z = (a0 * acc[d4 + 4][rq * 4 + 2] + a1 * u.z) * inv;
        o.w = (a0 * acc[d4 + 4][rq * 4 + 3] + a1 * u.w) * inv;
        *(float4*)(orow + d) = o;
      }
    }
  }
}

// ---------------------------------------------------------------------------
extern "C" void kernel_launch(void* const* d_in, const int* in_sizes, int n_in,
                              void* d_out, int out_size, void* d_ws, size_t ws_size,
                              hipStream_t stream) {
  const float* enc = (const float*)d_in[0];
  const float* dec = (const float*)d_in[1];
  float* out = (float*)d_out;

  u16* ws_img = (u16*)d_ws;

  convert_enc<<<BN * (S / 64), 256, 0, stream>>>(enc, ws_img);
  attn_kernel<<<BN * (S / 128), 512, 0, stream>>>(ws_img, dec, out);
}

// Round 11
// 191.258 us; speedup vs baseline: 3.0392x; 3.0392x over previous
//
#include <hip/hip_runtime.h>

typedef unsigned short u16;
typedef unsigned int u32;
typedef __attribute__((ext_vector_type(8))) _Float16 half8;
typedef __attribute__((ext_vector_type(2))) __fp16 fp16x2;
typedef __attribute__((ext_vector_type(16))) float f32x16;

#define MFMA32(A, B, C) __builtin_amdgcn_mfma_f32_32x32x16_f16(A, B, C, 0, 0, 0)

constexpr int BN = 8;     // batches
constexpr int S = 4096;   // seq len
constexpr int D = 256;    // feature dim
constexpr int KB = 32;    // K/V tile rows
constexpr int NT = S / KB;            // 128 tiles
constexpr int TILE_U16 = KB * D;      // 8192 u16 = 16 KiB per image
constexpr int TP_U16 = 2 * TILE_U16;  // 32 KiB tile pack (enc|encT)

__device__ __forceinline__ u32 pk2h(float a, float b) {  // RNE (conversion path)
  union { _Float16 h[2]; u32 u; } x;
  x.h[0] = (_Float16)a; x.h[1] = (_Float16)b;
  return x.u;
}

__device__ __forceinline__ u32 pkrtz(float a, float b) {  // 1-inst pack (hot loop)
  union { fp16x2 h; u32 u; } x;
  x.h = __builtin_amdgcn_cvt_pkrtz(a, b);
  return x.u;
}

__device__ __forceinline__ void gload_lds16(const void* g, void* l) {
  __builtin_amdgcn_global_load_lds((__attribute__((address_space(1))) void*)(void*)g,
                                   (__attribute__((address_space(3))) void*)l, 16, 0, 0);
}

// ---------------------------------------------------------------------------
// Convert enc (f32) into MFMA-fragment-ordered f16 tile packs (validated):
// pack(b,t) = [ enc_img | encT_img ], 32 KiB contiguous; all attn ds_reads
// lane-linear b128, staging a plain linear global_load_lds copy.
// ---------------------------------------------------------------------------
__global__ __launch_bounds__(256) void convert_enc(const float* __restrict__ enc,
                                                   u16* __restrict__ ws) {
  const int blk = blockIdx.x;
  const int b = blk & 7;
  const int tp = blk >> 3;  // tile pair 0..63
  const int tid = threadIdx.x;

  const float* encb = enc + (size_t)b * S * D;

  // ---- phase A: enc images, 2 tiles x 1024 groups ----
#pragma unroll
  for (int it = 0; it < 8; ++it) {
    int gg = it * 256 + tid;        // 0..2047
    int t = tp * 2 + (gg >> 10);
    int g = gg & 1023;              // (c*2+h)*32 + i
    int i = g & 31;
    int ch = g >> 5;
    int d0 = ch * 8;
    const float* src = encb + (size_t)(t * 32 + i) * D + d0;
    float4 x = *(const float4*)src;
    float4 y = *(const float4*)(src + 4);
    uint4 o;
    o.x = pk2h(x.x, x.y); o.y = pk2h(x.z, x.w);
    o.z = pk2h(y.x, y.y); o.w = pk2h(y.z, y.w);
    *(uint4*)(ws + (size_t)(b * NT + t) * TP_U16 + g * 8) = o;
  }

  // ---- phase B: encT images, 2 tiles x 128 blocklets (8i x 8d) ----
  {
    int t = tp * 2 + (tid >> 7);
    int r = tid & 127;
    int o = r >> 5;       // i-oct: ic=o>>1, h=o&1
    int e = r & 31;       // d-oct
    int i0 = o * 8;
    int d0 = e * 8;
    float v[8][8];
#pragma unroll
    for (int rr = 0; rr < 8; ++rr) {
      const float* src = encb + (size_t)(t * 32 + i0 + rr) * D + d0;
      *(float4*)&v[rr][0] = *(const float4*)src;
      *(float4*)&v[rr][4] = *(const float4*)(src + 4);
    }
    int dsub = e >> 2;
    u16* dst = ws + (size_t)(b * NT + t) * TP_U16 + TILE_U16 +
               ((dsub * 4 + o) * 32 + (e & 3) * 8) * 8;
#pragma unroll
    for (int k = 0; k < 8; ++k) {
      uint4 q;
      q.x = pk2h(v[0][k], v[1][k]); q.y = pk2h(v[2][k], v[3][k]);
      q.z = pk2h(v[4][k], v[5][k]); q.w = pk2h(v[6][k], v[7][k]);
      *(uint4*)(dst + k * 8) = q;
    }
  }
}

// ---------------------------------------------------------------------------
// Flash attention, 8 waves, in-block split-K, FUSED-INTERLEAVED pass:
//   pass j (per stream, tile t=2j+kh), ONE barrier:
//     stage(t+1) | { per step c: 4 ds_read (enc c,c+1; encT c,c+1)
//                               + 4 MFMA (QK s0,s1; PV acc[c/2] x2) } | SM(t)
// QK(t) and PV(t-1) interleaved at source so the scheduler always has
// independent MFMA + ds_read work in the same window. Reductions via
// __shfl_xor (r8-validated; the permlane asm variant coalesced registers
// and silently broke the max reduction -- r10 lesson).
// enc ring = 2 slots, encT ring = 3 slots per stream (160 KiB total).
// ---------------------------------------------------------------------------
__global__ __launch_bounds__(512, 2) void attn_kernel(const u16* __restrict__ ws_img,
                                                      const float* __restrict__ dec,
                                                      float* __restrict__ out) {
  // [stream][slot]: slot 0-1 = enc ring, slot 2-4 = encT ring. 160 KiB total.
  __shared__ u16 LDSA[2][5][TILE_U16];

  const int tid = threadIdx.x;
  const int w = tid >> 6;
  const int wq = w & 3;
  const int kh = w >> 2;
  const int lane = tid & 63;
  const int h = lane >> 5;
  const int l31 = lane & 31;

  const int blk = blockIdx.x;
  const int b = blk & 7;               // batch -> XCD affinity
  const int q0 = (blk >> 3) << 7;      // QBLK = 128
  const int qw = q0 + wq * 32;

  const u16* packs = ws_img + (size_t)b * NT * TP_U16;
  const float* decb = dec + (size_t)b * S * D;

  // ---- Q fragments (B-operand): lane q=l31, k=c*16+h*8+j; pre-scaled log2e ----
  const float LOG2E = 1.4426950408889634f;
  half8 qf[16];
#pragma unroll
  for (int c = 0; c < 16; ++c) {
    const float* p = decb + (size_t)(qw + l31) * D + c * 16 + h * 8;
    float4 x = *(const float4*)p;
    float4 y = *(const float4*)(p + 4);
    union { u32 u[4]; half8 v; } uu;
    uu.u[0] = pk2h(x.x * LOG2E, x.y * LOG2E);
    uu.u[1] = pk2h(x.z * LOG2E, x.w * LOG2E);
    uu.u[2] = pk2h(y.x * LOG2E, y.y * LOG2E);
    uu.u[3] = pk2h(y.z * LOG2E, y.w * LOG2E);
    qf[c] = uu.v;
  }

  f32x16 acc[8] = {};   // O^T: [dsub]; lane: q=l31, d=dsub*32+(r&3)+8*(r>>2)+4h
  float mrun = -1e30f;  // running max (log2 domain)
  float lrun = 0.f;

  const int hoff = h * 512 + l31 * 16;

  // stage tile t of this stream: enc half -> enc slot eslot, encT -> 2+tslot.
  auto stagef = [&](int t, int eslot, int tslot) {
    const char* gs = (const char*)(packs + (size_t)t * TP_U16) +
                     (wq >> 1) * 16384 + (wq & 1) * 8192 + lane * 16;
    char* ls = (char*)&LDSA[kh][(wq < 2) ? eslot : (2 + tslot)][0] + (wq & 1) * 8192;
#pragma unroll
    for (int it = 0; it < 8; ++it)
      gload_lds16(gs + it * 1024, ls + it * 1024);
  };

  // SM(t): online softmax (log2 domain), defer-max, pack -> bfr
  auto smf = [&](f32x16 st, half8* bfr) {
    float x0 = fmaxf(fmaxf(st[0], st[1]), fmaxf(st[2], st[3]));
    float x1 = fmaxf(fmaxf(st[4], st[5]), fmaxf(st[6], st[7]));
    float x2 = fmaxf(fmaxf(st[8], st[9]), fmaxf(st[10], st[11]));
    float x3 = fmaxf(fmaxf(st[12], st[13]), fmaxf(st[14], st[15]));
    float tm = fmaxf(fmaxf(x0, x1), fmaxf(x2, x3));
    tm = fmaxf(tm, __shfl_xor(tm, 32));
    if (__any(tm > mrun + 11.5f)) {
      float mnew = fmaxf(mrun, tm);
      float alpha = __builtin_amdgcn_exp2f(mrun - mnew);
      mrun = mnew;
      lrun *= alpha;
#pragma unroll
      for (int ds = 0; ds < 8; ++ds)
#pragma unroll
        for (int r = 0; r < 16; ++r) acc[ds][r] *= alpha;
    }
#pragma unroll
    for (int r = 0; r < 16; ++r) st[r] = __builtin_amdgcn_exp2f(st[r] - mrun);
    float y0 = (st[0] + st[1]) + (st[2] + st[3]);
    float y1 = (st[4] + st[5]) + (st[6] + st[7]);
    float y2 = (st[8] + st[9]) + (st[10] + st[11]);
    float y3 = (st[12] + st[13]) + (st[14] + st[15]);
    float rs = (y0 + y1) + (y2 + y3);
    rs += __shfl_xor(rs, 32);
    lrun += rs;

    u32 pkw[8];
#pragma unroll
    for (int rq = 0; rq < 4; ++rq) {
      pkw[rq * 2 + 0] = pkrtz(st[rq * 4 + 0], st[rq * 4 + 1]);
      pkw[rq * 2 + 1] = pkrtz(st[rq * 4 + 2], st[rq * 4 + 3]);
    }
#pragma unroll
    for (int ic = 0; ic < 2; ++ic) {
      u32 own0 = pkw[(2 * ic + h) * 2 + 0];
      u32 own1 = pkw[(2 * ic + h) * 2 + 1];
      u32 send0 = pkw[(2 * ic + 1 - h) * 2 + 0];
      u32 send1 = pkw[(2 * ic + 1 - h) * 2 + 1];
      u32 r0 = (u32)__shfl_xor((int)send0, 32);
      u32 r1 = (u32)__shfl_xor((int)send1, 32);
      union { u32 u[4]; half8 v; } bb;
      bb.u[0] = h ? r0 : own0;
      bb.u[1] = h ? r1 : own1;
      bb.u[2] = h ? own0 : r0;
      bb.u[3] = h ? own1 : r1;
      bfr[ic] = bb.v;
    }
  };

  half8 bfrA[2], bfrB[2];
  int e_cur = 0;
  int t_prev = 2, t_cur = 0, t_next = 1;

  // prologue: stage tile_0 of own stream
  stagef(kh, 0, 0);
  __syncthreads();

  // ---- peeled pass j=0: stage(t1) | QK(t0) | SM(t0) ----
  {
    stagef(2 + kh, e_cur ^ 1, t_next);
    const char* eb = (const char*)&LDSA[kh][e_cur][0];
    f32x16 s0 = {}, s1 = {};
    __builtin_amdgcn_s_setprio(1);
#pragma unroll
    for (int c = 0; c < 16; c += 2) {
      half8 a0 = *(const half8*)(eb + (c + 0) * 1024 + hoff);
      half8 a1 = *(const half8*)(eb + (c + 1) * 1024 + hoff);
      s0 = MFMA32(a0, qf[c + 0], s0);
      s1 = MFMA32(a1, qf[c + 1], s1);
    }
    __builtin_amdgcn_s_setprio(0);
    smf(s0 + s1, bfrA);
    __syncthreads();
    e_cur ^= 1;
    t_prev = t_cur; t_cur = t_next; t_next = (t_next == 2) ? 0 : t_next + 1;
  }

  // ---- main loop j=1..63: stage(t+1) | fused QK(t)+PV(t-1) | SM(t) ----
#pragma unroll 1
  for (int j = 1; j < 64; ++j) {
    if (j < 63) stagef(2 * (j + 1) + kh, e_cur ^ 1, t_next);

    f32x16 s0 = {}, s1 = {};
    {
      const char* eb = (const char*)&LDSA[kh][e_cur][0];
      const char* tb = (const char*)&LDSA[kh][2 + t_prev][0];
      __builtin_amdgcn_s_setprio(1);
#pragma unroll
      for (int c = 0; c < 16; c += 2) {
        half8 a0 = *(const half8*)(eb + (c + 0) * 1024 + hoff);
        half8 a1 = *(const half8*)(eb + (c + 1) * 1024 + hoff);
        half8 v0 = *(const half8*)(tb + (c + 0) * 1024 + hoff);
        half8 v1 = *(const half8*)(tb + (c + 1) * 1024 + hoff);
        s0 = MFMA32(a0, qf[c + 0], s0);
        s1 = MFMA32(a1, qf[c + 1], s1);
        acc[c >> 1] = MFMA32(v0, bfrA[0], acc[c >> 1]);
        acc[c >> 1] = MFMA32(v1, bfrA[1], acc[c >> 1]);
      }
      __builtin_amdgcn_s_setprio(0);
    }

    smf(s0 + s1, bfrB);
    bfrA[0] = bfrB[0]; bfrA[1] = bfrB[1];

    __syncthreads();
    e_cur ^= 1;
    t_prev = t_cur; t_cur = t_next; t_next = (t_next == 2) ? 0 : t_next + 1;
  }

  // ---- drain: PV of last tile ----
  {
    const char* tb = (const char*)&LDSA[kh][2 + t_prev][0];
    __builtin_amdgcn_s_setprio(1);
#pragma unroll
    for (int c = 0; c < 16; c += 2) {
      half8 v0 = *(const half8*)(tb + (c + 0) * 1024 + hoff);
      half8 v1 = *(const half8*)(tb + (c + 1) * 1024 + hoff);
      acc[c >> 1] = MFMA32(v0, bfrA[0], acc[c >> 1]);
      acc[c >> 1] = MFMA32(v1, bfrA[1], acc[c >> 1]);
    }
    __builtin_amdgcn_s_setprio(0);
  }
  __syncthreads();

  // ---- merge the two K-streams through LDS (r4-validated) ----
  float* fb = (float*)&LDSA[0][0][0];
  constexpr int XS = 20;
  float* mlb = fb + 30208;

  if (kh == 1) {
    if (lane < 32) {
      mlb[wq * 64 + lane] = mrun;
      mlb[wq * 64 + 32 + lane] = lrun;
    }
#pragma unroll
    for (int d4 = 0; d4 < 4; ++d4) {
      float* dst = fb + ((wq * 4 + d4) * 64 + lane) * XS;
#pragma unroll
      for (int r4 = 0; r4 < 4; ++r4) {
        float4 v;
        v.x = acc[d4][r4 * 4 + 0]; v.y = acc[d4][r4 * 4 + 1];
        v.z = acc[d4][r4 * 4 + 2]; v.w = acc[d4][r4 * 4 + 3];
        *(float4*)(dst + r4 * 4) = v;
      }
    }
  }
  __syncthreads();

  float a0 = 0.f, a1 = 0.f, inv = 0.f;
  const int q = qw + l31;
  float* orow = out + ((size_t)(b * S + q)) * D;
  if (kh == 0) {
    float m1 = mlb[wq * 64 + l31];
    float l1 = mlb[wq * 64 + 32 + l31];
    float mn = fmaxf(mrun, m1);
    a0 = __builtin_amdgcn_exp2f(mrun - mn);
    a1 = __builtin_amdgcn_exp2f(m1 - mn);
    inv = 1.0f / (a0 * lrun + a1 * l1);
#pragma unroll
    for (int d4 = 0; d4 < 4; ++d4) {
      const float* src = fb + ((wq * 4 + d4) * 64 + lane) * XS;
#pragma unroll
      for (int rq = 0; rq < 4; ++rq) {
        float4 u = *(const float4*)(src + rq * 4);
        int d = d4 * 32 + rq * 8 + h * 4;
        float4 o;
        o.x = (a0 * acc[d4][rq * 4 + 0] + a1 * u.x) * inv;
        o.y = (a0 * acc[d4][rq * 4 + 1] + a1 * u.y) * inv;
        o.z = (a0 * acc[d4][rq * 4 + 2] + a1 * u.z) * inv;
        o.w = (a0 * acc[d4][rq * 4 + 3] + a1 * u.w) * inv;
        *(float4*)(orow + d) = o;
      }
    }
  }
  __syncthreads();

  if (kh == 1) {
#pragma unroll
    for (int d4 = 0; d4 < 4; ++d4) {
      float* dst = fb + ((wq * 4 + d4) * 64 + lane) * XS;
#pragma unroll
      for (int r4 = 0; r4 < 4; ++r4) {
        float4 v;
        v.x = acc[d4 + 4][r4 * 4 + 0]; v.y = acc[d4 + 4][r4 * 4 + 1];
        v.z = acc[d4 + 4][r4 * 4 + 2]; v.w = acc[d4 + 4][r4 * 4 + 3];
        *(float4*)(dst + r4 * 4) = v;
      }
    }
  }
  __syncthreads();

  if (kh == 0) {
#pragma unroll
    for (int d4 = 0; d4 < 4; ++d4) {
      const float* src = fb + ((wq * 4 + d4) * 64 + lane) * XS;
#pragma unroll
      for (int rq = 0; rq < 4; ++rq) {
        float4 u = *(const float4*)(src + rq * 4);
        int d = (d4 + 4) * 32 + rq * 8 + h * 4;
        float4 o;
        o.x = (a0 * acc[d4 + 4][rq * 4 + 0] + a1 * u.x) * inv;
        o.y = (a0 * acc[d4 + 4][rq * 4 + 1] + a1 * u.y) * inv;
        o.z = (a0 * acc[d4 + 4][rq * 4 + 2] + a1 * u.z) * inv;
        o.w = (a0 * acc[d4 + 4][rq * 4 + 3] + a1 * u.w) * inv;
        *(float4*)(orow + d) = o;
      }
    }
  }
}

// ---------------------------------------------------------------------------
extern "C" void kernel_launch(void* const* d_in, const int* in_sizes, int n_in,
                              void* d_out, int out_size, void* d_ws, size_t ws_size,
                              hipStream_t stream) {
  const float* enc = (const float*)d_in[0];
  const float* dec = (const float*)d_in[1];
  float* out = (float*)d_out;

  u16* ws_img = (u16*)d_ws;

  convert_enc<<<BN * (S / 64), 256, 0, stream>>>(enc, ws_img);
  attn_kernel<<<BN * (S / 128), 512, 0, stream>>>(ws_img, dec, out);
}